// Round 9
// baseline (268.044 us; speedup 1.0000x reference)
//
#include <hip/hip_runtime.h>
#include <math.h>

#define BB  4
#define SS  1024
#define DD  512
#define HH  8
#define DHD 64
#define PL  2097152      // elements per Q/K/V/Ob plane (also B*S*D)

constexpr float LN_EPS = 1e-5f;

using half4 = __attribute__((ext_vector_type(4))) _Float16;
using half8 = __attribute__((ext_vector_type(8))) _Float16;
using f32x4 = __attribute__((ext_vector_type(4))) float;

__device__ __forceinline__ half8 negh(half8 a) {
    union { half8 h; unsigned int u[4]; } t;
    t.h = a;
    #pragma unroll
    for (int i = 0; i < 4; ++i) t.u[i] ^= 0x80008000u;
    return t.h;
}
// 64-wide swizzled rows (XOR (row&7)<<3, 8-half granules): conflict-free b128
__device__ __forceinline__ half8 ldh64(const unsigned short* p, int row, int col) {
    return *(const half8*)(p + row * 64 + (col ^ ((row & 7) << 3)));
}
#define MFMA16(acc, a, b) acc = __builtin_amdgcn_mfma_f32_16x16x32_f16(a, b, acc, 0, 0, 0)

// ---------------------------------------------------------------------------
// Kernel 1: complex projection, fp32 inputs converted to fp16 in-kernel
// (coalesced staging: row = tid>>2, 4 lanes x 64B contiguous per row; the
// round-6 regression was the 64-rows-per-instr map, not conversion cost).
// Waves split 2x2 (32m x 32e each): fragment reads 20 -> 16 b128/iter.
// Q/K out: fp16 r/i planes [BH][S][64]; V out: pre-transposed [BH][64][S].
// ---------------------------------------------------------------------------
__global__ __launch_bounds__(256, 4)
void proj_kernel(const float2* __restrict__ qin, const float2* __restrict__ kin,
                 const float2* __restrict__ vin,
                 const float2* __restrict__ Wq, const float2* __restrict__ Wk,
                 const float2* __restrict__ Wv,
                 const float2* __restrict__ bq, const float2* __restrict__ bk,
                 const float2* __restrict__ bv,
                 unsigned short* __restrict__ QG, unsigned short* __restrict__ KG,
                 unsigned short* __restrict__ VG) {
    const float2* X; const float2* W; const float2* bias; unsigned short* outP;
    if (blockIdx.z == 0)      { X = qin; W = Wq; bias = bq; outP = QG; }
    else if (blockIdx.z == 1) { X = kin; W = Wk; bias = bk; outP = KG; }
    else                      { X = vin; W = Wv; bias = bv; outP = VG; }
    const bool isV = (blockIdx.z == 2);

    __shared__ unsigned short Xs[2][4096];   // [r,i][64 m][64 d] swizzled
    __shared__ unsigned short Ws[2][4096];   // [r,i][64 e][64 d] swizzled

    const int tid  = threadIdx.x;
    const int w    = tid >> 6;
    const int lane = tid & 63;
    const int quad = lane >> 4;
    const int l15  = lane & 15;
    const int m0   = blockIdx.x * 64;
    const int h    = blockIdx.y;
    const int e0   = h * 64;
    const int sw   = w & 1;        // m-half
    const int tw   = w >> 1;       // e-half

    const int srow = tid >> 2;          // 0..63 staging row
    const int sc   = (tid & 3) * 16;    // complex col base (16 complex/thread)
    const int ga   = sc >> 3;           // granule base (even)
    const int go0  = srow * 64 + ((ga ^ (srow & 7)) << 3);
    const int go1  = srow * 64 + (((ga + 1) ^ (srow & 7)) << 3);

    f32x4 Sr[2][2], Si[2][2];
    #pragma unroll
    for (int a = 0; a < 2; ++a)
        #pragma unroll
        for (int c = 0; c < 2; ++c) { Sr[a][c] = (f32x4)0.f; Si[a][c] = (f32x4)0.f; }

    for (int dc = 0; dc < DD; dc += 64) {
        if (dc) __syncthreads();
        // ---- X chunk: fp32 complex -> fp16 r/i, coalesced ----
        {
            const float4* xp = (const float4*)(X + (size_t)(m0 + srow) * DD + dc + sc);
            union { _Float16 h[16]; uint4 q[2]; } hr, hi;
            #pragma unroll
            for (int j = 0; j < 8; ++j) {
                float4 t = xp[j];
                hr.h[2*j]   = (_Float16)t.x; hi.h[2*j]   = (_Float16)t.y;
                hr.h[2*j+1] = (_Float16)t.z; hi.h[2*j+1] = (_Float16)t.w;
            }
            *(uint4*)&Xs[0][go0] = hr.q[0]; *(uint4*)&Xs[0][go1] = hr.q[1];
            *(uint4*)&Xs[1][go0] = hi.q[0]; *(uint4*)&Xs[1][go1] = hi.q[1];
        }
        // ---- W chunk: fp32 complex -> fp16 r/i, coalesced ----
        {
            const float4* wp = (const float4*)(W + (size_t)(e0 + srow) * DD + dc + sc);
            union { _Float16 h[16]; uint4 q[2]; } hr, hi;
            #pragma unroll
            for (int j = 0; j < 8; ++j) {
                float4 t = wp[j];
                hr.h[2*j]   = (_Float16)t.x; hi.h[2*j]   = (_Float16)t.y;
                hr.h[2*j+1] = (_Float16)t.z; hi.h[2*j+1] = (_Float16)t.w;
            }
            *(uint4*)&Ws[0][go0] = hr.q[0]; *(uint4*)&Ws[0][go1] = hr.q[1];
            *(uint4*)&Ws[1][go0] = hi.q[0]; *(uint4*)&Ws[1][go1] = hi.q[1];
        }
        __syncthreads();

        #pragma unroll
        for (int kc = 0; kc < 2; ++kc) {
            const int dl = kc * 32 + quad * 8;
            half8 xr[2], xi[2], xmi[2], wr[2], wi[2];
            #pragma unroll
            for (int mt = 0; mt < 2; ++mt) {
                const int mrow = sw * 32 + mt * 16 + l15;
                xr[mt]  = ldh64(Xs[0], mrow, dl);
                xi[mt]  = ldh64(Xs[1], mrow, dl);
                xmi[mt] = negh(xi[mt]);
            }
            #pragma unroll
            for (int et = 0; et < 2; ++et) {
                const int er = tw * 32 + et * 16 + l15;
                wr[et] = ldh64(Ws[0], er, dl);
                wi[et] = ldh64(Ws[1], er, dl);
            }
            #pragma unroll
            for (int mt = 0; mt < 2; ++mt)
                #pragma unroll
                for (int et = 0; et < 2; ++et) {
                    MFMA16(Sr[mt][et], xr[mt],  wr[et]);   // Sr = XrWr - XiWi
                    MFMA16(Sr[mt][et], xmi[mt], wi[et]);
                    MFMA16(Si[mt][et], xr[mt],  wi[et]);   // Si = XrWi + XiWr
                    MFMA16(Si[mt][et], xi[mt],  wr[et]);
                }
        }
    }

    // epilogue: + bias, fp16, write planes (V transposed)
    #pragma unroll
    for (int mt = 0; mt < 2; ++mt)
        #pragma unroll
        for (int et = 0; et < 2; ++et) {
            const int col = tw * 32 + et * 16 + l15;
            float2 bb = bias[e0 + col];
            #pragma unroll
            for (int reg = 0; reg < 4; ++reg) {
                int m = m0 + sw * 32 + mt * 16 + quad * 4 + reg;
                int b = m >> 10;
                int s = m & 1023;
                int bh = b * HH + h;
                union { _Float16 h; unsigned short u; } cr, ci;
                cr.h = (_Float16)(Sr[mt][et][reg] + bb.x);
                ci.h = (_Float16)(Si[mt][et][reg] + bb.y);
                size_t o = isV ? ((size_t)bh * DHD + col) * SS + s
                               : ((size_t)bh * SS + s) * DHD + col;
                outP[0 * PL + o] = cr.u;
                outP[1 * PL + o] = ci.u;
            }
        }
}

// ---------------------------------------------------------------------------
// Kernel 2: fp16 MFMA flash attention, S^T formulation (unchanged, round 8).
// ---------------------------------------------------------------------------
#define AWID 72
__global__ __launch_bounds__(256, 2)
void attn_kernel(const unsigned short* __restrict__ QG, const unsigned short* __restrict__ KG,
                 const unsigned short* __restrict__ VG,
                 unsigned short* __restrict__ ObR, unsigned short* __restrict__ ObI) {
    __shared__ unsigned short Ks[2][64 * AWID];   // [r,i][k][d]
    __shared__ unsigned short Vt[2][64 * AWID];   // [r,i][d][k]
    __shared__ unsigned short Ps[2][64 * AWID];   // [r,i][q][k]
    __shared__ float lbuf[2][2][64];              // [plane][k-half][q]

    const int n   = blockIdx.x;
    const int bh  = (n & 7) * 4 + (n >> 7);       // XCD-local bh group
    const int q0  = ((n >> 3) & 15) * 64;
    const int b   = bh >> 3;
    const int h   = bh & 7;

    const int tid  = threadIdx.x;
    const int w    = tid >> 6;
    const int lane = tid & 63;
    const int quad = lane >> 4;
    const int l15  = lane & 15;
    const int sw   = w & 1;        // q-half (both phases)
    const int tw   = w >> 1;       // k-half (scores) / d-half (PV)

    half8 qfr[2][2], qfi[2][2], qfmi[2][2];       // [qt][kc]
    #pragma unroll
    for (int qt = 0; qt < 2; ++qt)
        #pragma unroll
        for (int kc = 0; kc < 2; ++kc) {
            size_t qa = ((size_t)bh * SS + q0 + sw * 32 + qt * 16 + l15) * DHD + kc * 32 + quad * 8;
            qfr[qt][kc]  = *(const half8*)(QG + qa);
            qfi[qt][kc]  = *(const half8*)(QG + PL + qa);
            qfmi[qt][kc] = negh(qfi[qt][kc]);
        }

    f32x4 acc[2][2][4];            // [qt][dt][PrVr,PrVi,PiVr,PiVi]
    #pragma unroll
    for (int qt = 0; qt < 2; ++qt)
        #pragma unroll
        for (int dt = 0; dt < 2; ++dt)
            #pragma unroll
            for (int p = 0; p < 4; ++p) acc[qt][dt][p] = (f32x4)0.f;
    float lacc[2][2] = {{0.f, 0.f}, {0.f, 0.f}};  // [qt][plane]

    const int srow = tid >> 3;      // 0..31
    const int sg   = (tid & 7) * 8; // granule col

    for (int kt = 0; kt < SS; kt += 64) {
        __syncthreads();
        #pragma unroll
        for (int p = 0; p < 2; ++p)
            #pragma unroll
            for (int it = 0; it < 2; ++it) {
                const int r = it * 32 + srow;
                *(uint4*)&Ks[p][r * AWID + sg] =
                    *(const uint4*)(KG + (size_t)p * PL + ((size_t)bh * SS + kt + r) * DHD + sg);
                *(uint4*)&Vt[p][r * AWID + sg] =
                    *(const uint4*)(VG + (size_t)p * PL + ((size_t)bh * DHD + r) * SS + kt + sg);
            }
        __syncthreads();

        f32x4 Sr[2][2], Si[2][2];   // [kt2][qt]
        #pragma unroll
        for (int a = 0; a < 2; ++a)
            #pragma unroll
            for (int c = 0; c < 2; ++c) { Sr[a][c] = (f32x4)0.f; Si[a][c] = (f32x4)0.f; }
        #pragma unroll
        for (int kc = 0; kc < 2; ++kc) {
            #pragma unroll
            for (int kt2 = 0; kt2 < 2; ++kt2) {
                const int krow = tw * 32 + kt2 * 16 + l15;
                half8 akr = *(const half8*)&Ks[0][krow * AWID + kc * 32 + quad * 8];
                half8 aki = *(const half8*)&Ks[1][krow * AWID + kc * 32 + quad * 8];
                #pragma unroll
                for (int qt = 0; qt < 2; ++qt) {
                    MFMA16(Sr[kt2][qt], akr, qfr[qt][kc]);    // K_r . Q_r
                    MFMA16(Sr[kt2][qt], aki, qfmi[qt][kc]);   // -K_i . Q_i
                    MFMA16(Si[kt2][qt], aki, qfr[qt][kc]);    // K_i . Q_r
                    MFMA16(Si[kt2][qt], akr, qfi[qt][kc]);    // K_r . Q_i
                }
            }
        }

        #pragma unroll
        for (int kt2 = 0; kt2 < 2; ++kt2)
            #pragma unroll
            for (int qt = 0; qt < 2; ++qt) {
                half4 pr, pi;
                float sr_ = 0.f, si_ = 0.f;
                #pragma unroll
                for (int reg = 0; reg < 4; ++reg) {
                    float er = __expf(Sr[kt2][qt][reg] * 0.125f);
                    float ei = __expf(Si[kt2][qt][reg] * 0.125f);
                    pr[reg] = (_Float16)er;
                    pi[reg] = (_Float16)ei;
                    sr_ += (float)pr[reg];   // l from rounded p: consistent weights
                    si_ += (float)pi[reg];
                }
                lacc[qt][0] += sr_;
                lacc[qt][1] += si_;
                const int qrow = sw * 32 + qt * 16 + l15;
                const int kcol = tw * 32 + kt2 * 16 + quad * 4;
                *(half4*)&Ps[0][qrow * AWID + kcol] = pr;
                *(half4*)&Ps[1][qrow * AWID + kcol] = pi;
            }
        __syncthreads();

        #pragma unroll
        for (int kc = 0; kc < 2; ++kc) {
            half8 ap[2][2];   // [qt][plane]
            #pragma unroll
            for (int qt = 0; qt < 2; ++qt) {
                const int qrow = sw * 32 + qt * 16 + l15;
                ap[qt][0] = *(const half8*)&Ps[0][qrow * AWID + kc * 32 + quad * 8];
                ap[qt][1] = *(const half8*)&Ps[1][qrow * AWID + kc * 32 + quad * 8];
            }
            #pragma unroll
            for (int dt = 0; dt < 2; ++dt) {
                const int drow = tw * 32 + dt * 16 + l15;
                half8 bvr = *(const half8*)&Vt[0][drow * AWID + kc * 32 + quad * 8];
                half8 bvi = *(const half8*)&Vt[1][drow * AWID + kc * 32 + quad * 8];
                #pragma unroll
                for (int qt = 0; qt < 2; ++qt) {
                    MFMA16(acc[qt][dt][0], ap[qt][0], bvr);
                    MFMA16(acc[qt][dt][1], ap[qt][0], bvi);
                    MFMA16(acc[qt][dt][2], ap[qt][1], bvr);
                    MFMA16(acc[qt][dt][3], ap[qt][1], bvi);
                }
            }
        }
    }

    __syncthreads();
    #pragma unroll
    for (int qt = 0; qt < 2; ++qt)
        #pragma unroll
        for (int p = 0; p < 2; ++p) {
            float v = lacc[qt][p];
            v += __shfl_xor(v, 16);
            v += __shfl_xor(v, 32);
            if (lane < 16) lbuf[p][tw][sw * 32 + qt * 16 + lane] = v;
        }
    __syncthreads();

    #pragma unroll
    for (int qt = 0; qt < 2; ++qt)
        #pragma unroll
        for (int reg = 0; reg < 4; ++reg) {
            const int qloc = sw * 32 + qt * 16 + quad * 4 + reg;
            const float ir = 1.f / (lbuf[0][0][qloc] + lbuf[0][1][qloc]);
            const float ii = 1.f / (lbuf[1][0][qloc] + lbuf[1][1][qloc]);
            #pragma unroll
            for (int dt = 0; dt < 2; ++dt) {
                const int d = tw * 32 + dt * 16 + l15;
                union { _Float16 h; unsigned short u; } cr, ci;
                cr.h = (_Float16)(acc[qt][dt][0][reg] * ir - acc[qt][dt][3][reg] * ii);
                ci.h = (_Float16)(acc[qt][dt][1][reg] * ir + acc[qt][dt][2][reg] * ii);
                size_t o = ((size_t)b * SS + q0 + qloc) * DD + h * DHD + d;
                ObR[o] = cr.u;
                ObI[o] = ci.u;
            }
        }
}

// ---------------------------------------------------------------------------
// Kernel 3: residual + dual LayerNorm over D (biased var, eps inside sqrt)
// ---------------------------------------------------------------------------
__global__ __launch_bounds__(256)
void ln_kernel(const unsigned short* __restrict__ OrP, const unsigned short* __restrict__ OiP,
               const float2* __restrict__ Qin,
               const float* __restrict__ gr, const float* __restrict__ br,
               const float* __restrict__ gi, const float* __restrict__ bi,
               float2* __restrict__ out) {
    const int row = blockIdx.x;           // b*S + s
    const int tid = threadIdx.x;
    const size_t base = (size_t)row * DD;
    const int e0 = 2 * tid, e1 = 2 * tid + 1;

    union { unsigned int u; _Float16 h[2]; } tr, ti;
    tr.u = *(const unsigned int*)(OrP + base + e0);
    ti.u = *(const unsigned int*)(OiP + base + e0);
    float2 r0 = Qin[base + e0];
    float2 r1 = Qin[base + e1];
    float xr0 = (float)tr.h[0] + r0.x;
    float xr1 = (float)tr.h[1] + r1.x;
    float xi0 = (float)ti.h[0] + r0.y;
    float xi1 = (float)ti.h[1] + r1.y;

    float sr = xr0 + xr1;
    float si = xi0 + xi1;
    float qr = xr0 * xr0 + xr1 * xr1;
    float qi = xi0 * xi0 + xi1 * xi1;
    #pragma unroll
    for (int off = 32; off > 0; off >>= 1) {
        sr += __shfl_down(sr, off);
        si += __shfl_down(si, off);
        qr += __shfl_down(qr, off);
        qi += __shfl_down(qi, off);
    }
    __shared__ float red[4][4];
    __shared__ float stat[4];
    int lane = tid & 63, wid = tid >> 6;
    if (lane == 0) { red[wid][0] = sr; red[wid][1] = si; red[wid][2] = qr; red[wid][3] = qi; }
    __syncthreads();
    if (tid == 0) {
        sr = red[0][0] + red[1][0] + red[2][0] + red[3][0];
        si = red[0][1] + red[1][1] + red[2][1] + red[3][1];
        qr = red[0][2] + red[1][2] + red[2][2] + red[3][2];
        qi = red[0][3] + red[1][3] + red[2][3] + red[3][3];
        float mur = sr * (1.f / DD), mui = si * (1.f / DD);
        float vr = qr * (1.f / DD) - mur * mur;
        float vi = qi * (1.f / DD) - mui * mui;
        stat[0] = mur; stat[1] = mui;
        stat[2] = rsqrtf(vr + LN_EPS); stat[3] = rsqrtf(vi + LN_EPS);
    }
    __syncthreads();
    float mur = stat[0], mui = stat[1], rsr = stat[2], rsi = stat[3];
    out[base + e0] = make_float2((xr0 - mur) * rsr * gr[e0] + br[e0],
                                 (xi0 - mui) * rsi * gi[e0] + bi[e0]);
    out[base + e1] = make_float2((xr1 - mur) * rsr * gr[e1] + br[e1],
                                 (xi1 - mui) * rsi * gi[e1] + bi[e1]);
}

// ---------------------------------------------------------------------------
extern "C" void kernel_launch(void* const* d_in, const int* in_sizes, int n_in,
                              void* d_out, int out_size, void* d_ws, size_t ws_size,
                              hipStream_t stream) {
    const float2* q  = (const float2*)d_in[0];
    const float2* k  = (const float2*)d_in[1];
    const float2* v  = (const float2*)d_in[2];
    const float2* Wq = (const float2*)d_in[3];
    const float2* bq = (const float2*)d_in[4];
    const float2* Wk = (const float2*)d_in[5];
    const float2* bk = (const float2*)d_in[6];
    const float2* Wv = (const float2*)d_in[7];
    const float2* bv = (const float2*)d_in[8];
    const float*  gr = (const float*)d_in[9];
    const float*  br = (const float*)d_in[10];
    const float*  gi = (const float*)d_in[11];
    const float*  bi = (const float*)d_in[12];

    // workspace (fp16 elements): Q/K/V planes + Ob planes (~32 MB)
    unsigned short* QG  = (unsigned short*)d_ws;           // 2*PL  [BH][S][64]
    unsigned short* KG  = QG + (size_t)2 * PL;             // 2*PL  [BH][S][64]
    unsigned short* VG  = KG + (size_t)2 * PL;             // 2*PL  [BH][64][S] (transposed)
    unsigned short* ObR = VG + (size_t)2 * PL;             // PL
    unsigned short* ObI = ObR + (size_t)PL;                // PL

    proj_kernel<<<dim3(64, 8, 3), 256, 0, stream>>>(q, k, v, Wq, Wk, Wv, bq, bk, bv, QG, KG, VG);
    attn_kernel<<<dim3(512), 256, 0, stream>>>(QG, KG, VG, ObR, ObI);
    ln_kernel<<<dim3(BB * SS), 256, 0, stream>>>(ObR, ObI, q, gr, br, gi, bi, (float2*)d_out);
}